// Round 1
// baseline (854.768 us; speedup 1.0000x reference)
//
#include <hip/hip_runtime.h>

#define B_ 8
#define C_ 64
#define H_ 256
#define W_ 256
#define ST 32                 // output rows per wave/block strip
#define NCH 4                 // channels per thread
#define HW (H_ * W_)
#define WSTR (B_ * H_ * W_)   // weight tap stride in elements

// Rotating-partial-accumulator form: each arriving x row r contributes its 5
// horizontal taps to the 5 pending outputs h = r-2..r+2 (weight slice
// i = r-h+2). Live x state = current row (cur, 20 regs) + one-step prefetch
// (pf, 20 regs) instead of the old 5-row window (100 regs) whose exact-5
// rotation WAR-pinned x loads right before their FMAs (latency exposed every
// step: 30% VALUBusy / 25% HBM at minimal traffic). Weight slices are
// reloaded IN PLACE right after consumption -> also a full step of prefetch,
// zero extra registers. Masks fold into the pf->cur move.
__global__ __launch_bounds__(256, 4) void kpn5x5_v5(const float* __restrict__ x,
                                                    const float* __restrict__ wgt,
                                                    float* __restrict__ out) {
  const int tid  = threadIdx.x;
  const int lane = tid & 63;
  const int wv   = tid >> 6;               // 0..3
  const int w0   = blockIdx.x * 64;
  const int h0   = blockIdx.y * ST;
  const int bz   = blockIdx.z;             // = cgrp*8 + b (cgrp slowest ->
  const int b    = bz & 7;                 //   same-XCD weight sharing)
  const int c0   = (bz >> 3) * 16 + wv * NCH;

  // h-invariant per-thread column offsets (clamped) + 0/1 masks
  int   voff[5];
  float msk[5];
#pragma unroll
  for (int d = 0; d < 5; ++d) {
    const int col = w0 + lane - 2 + d;
    const bool ok = (col >= 0) && (col < W_);
    voff[d] = ok ? col : 0;
    msk[d]  = ok ? 1.0f : 0.0f;
  }

  // wave-uniform x/out bases -> force into SGPRs (saddr-form loads/stores)
  const float* xc;
  float* oc;
  {
    uint64_t px = (uint64_t)(x + (size_t)(b * C_ + c0) * HW);
    px = ((uint64_t)(uint32_t)__builtin_amdgcn_readfirstlane((int)(px >> 32)) << 32) |
         (uint64_t)(uint32_t)__builtin_amdgcn_readfirstlane((int)px);
    xc = (const float*)px;
    uint64_t po = (uint64_t)(out + (size_t)(b * C_ + c0) * HW);
    po = ((uint64_t)(uint32_t)__builtin_amdgcn_readfirstlane((int)(po >> 32)) << 32) |
         (uint64_t)(uint32_t)__builtin_amdgcn_readfirstlane((int)po);
    oc = (float*)po;
  }
  const float* wq = wgt + (size_t)b * HW + w0;   // block-uniform weight base

  float cur[NCH][5];   // taps of the arriving x row
  float pf[NCH][5];    // next x row (loaded one full step ahead)
  float wcs[5][5];     // per-pending-output weight slice (5 taps each)
  float acc[NCH][5];   // 5 rotating partial outputs per channel

#pragma unroll
  for (int ch = 0; ch < NCH; ++ch)
#pragma unroll
    for (int s = 0; s < 5; ++s) acc[ch][s] = 0.0f;

  // ---- prologue: pf <- x row h0-2 (consumed at step 0); wcs <- step-0 slices
  {
    const int r = h0 - 2;
    if (r >= 0) {
#pragma unroll
      for (int ch = 0; ch < NCH; ++ch) {
        const float* p = xc + ch * HW + r * W_;
#pragma unroll
        for (int d = 0; d < 5; ++d) pf[ch][d] = p[voff[d]];
      }
    } else {
#pragma unroll
      for (int ch = 0; ch < NCH; ++ch)
#pragma unroll
        for (int d = 0; d < 5; ++d) pf[ch][d] = 0.0f;
    }
    // step-0 segment j: tenant k=-j (phantom for j>0), slice i=j, slot (4-j)%5
#pragma unroll
    for (int j = 0; j < 5; ++j) {
      const int s = (4 - j) % 5;
      int hh = h0 - j;
      if (hh < 0) hh = 0;                       // clamp (phantom rows: garbage ok)
      const float* p = wq + (size_t)hh * W_;
#pragma unroll
      for (int d = 0; d < 5; ++d)
        wcs[s][d] = p[(size_t)(j * 5 + d) * WSTR + lane];
    }
  }

  // Step U (x row r = h0-2+U): mov pf->cur (masked), prefetch row r+1,
  // then 5 segments: segment j feeds tenant k=U-j (slot (S+4-j)%5, S=U%5)
  // and immediately reloads that slot's next-step weight slice in place.
  // Retiring segment (j==4) stores output h0+U-4 and resets its slot.
#define STEP(S, UO, DOST) do {                                               \
    const int u_ = ub + (UO);                                                \
    _Pragma("unroll")                                                        \
    for (int ch = 0; ch < NCH; ++ch)                                         \
      _Pragma("unroll")                                                      \
      for (int d = 0; d < 5; ++d) cur[ch][d] = pf[ch][d] * msk[d];           \
    {                                                                        \
      const int rb = h0 - 1 + u_;                                            \
      if ((unsigned)rb < (unsigned)H_) {                                     \
        _Pragma("unroll")                                                    \
        for (int ch = 0; ch < NCH; ++ch) {                                   \
          const float* p_ = xc + ch * HW + rb * W_;                          \
          _Pragma("unroll")                                                  \
          for (int d = 0; d < 5; ++d) pf[ch][d] = p_[voff[d]];               \
        }                                                                    \
      } else {                                                               \
        _Pragma("unroll")                                                    \
        for (int ch = 0; ch < NCH; ++ch)                                     \
          _Pragma("unroll")                                                  \
          for (int d = 0; d < 5; ++d) pf[ch][d] = 0.0f;                      \
      }                                                                      \
    }                                                                        \
    _Pragma("unroll")                                                        \
    for (int j = 0; j < 5; ++j) {                                            \
      const int s_ = ((S) + 4 - j) % 5;                                      \
      _Pragma("unroll")                                                      \
      for (int d = 0; d < 5; ++d) {                                          \
        const float wt_ = wcs[s_][d];                                        \
        _Pragma("unroll")                                                    \
        for (int ch = 0; ch < NCH; ++ch)                                     \
          acc[ch][s_] += cur[ch][d] * wt_;                                   \
      }                                                                      \
      if (j == 4) {                                                          \
        if (DOST) {                                                          \
          const size_t ob_ = (size_t)(h0 + u_ - 4) * W_ + w0 + lane;         \
          _Pragma("unroll")                                                  \
          for (int ch = 0; ch < NCH; ++ch)                                   \
            __builtin_nontemporal_store(acc[ch][(S)],                        \
                                        &oc[ob_ + (size_t)ch * HW]);         \
        }                                                                    \
        _Pragma("unroll")                                                    \
        for (int ch = 0; ch < NCH; ++ch) acc[ch][(S)] = 0.0f;                \
      }                                                                      \
      {                                                                      \
        int wr_ = (j == 4) ? (h0 + u_ + 1) : (h0 + u_ - j);                  \
        const int tb_ = (j == 4) ? 0 : (j + 1) * 5;                          \
        if (wr_ < 0) wr_ = 0;                                                \
        if (wr_ > H_ - 1) wr_ = H_ - 1;                                      \
        const float* pw_ = wq + (size_t)wr_ * W_;                            \
        _Pragma("unroll")                                                    \
        for (int d = 0; d < 5; ++d)                                          \
          wcs[s_][d] = pw_[(size_t)(tb_ + d) * WSTR + lane];                 \
      }                                                                      \
    }                                                                        \
  } while (0)

  int ub = 0;
  // 4 pipeline-fill steps (U=0..3): no stores, phantom slots get reset
  STEP(0, 0, false); STEP(1, 1, false); STEP(2, 2, false); STEP(3, 3, false);
  ub = 4;
  for (int g = 0; g < 6; ++g) {            // U = 4..33
    STEP(4, 0, true); STEP(0, 1, true); STEP(1, 2, true);
    STEP(2, 3, true); STEP(3, 4, true);
    ub += 5;
  }
  STEP(4, 0, true); STEP(0, 1, true);      // U = 34, 35  (32 stores total)
#undef STEP
}

extern "C" void kernel_launch(void* const* d_in, const int* in_sizes, int n_in,
                              void* d_out, int out_size, void* d_ws, size_t ws_size,
                              hipStream_t stream) {
  const float* x   = (const float*)d_in[0];
  const float* wgt = (const float*)d_in[1];
  float* out = (float*)d_out;
  dim3 grid(W_ / 64, H_ / ST, (C_ / (NCH * 4)) * B_);  // 4 x 8 x 32 = 1024 blocks
  dim3 block(256);
  kpn5x5_v5<<<grid, block, 0, stream>>>(x, wgt, out);
}

// Round 2
// 377.479 us; speedup vs baseline: 2.2644x; 2.2644x over previous
//
#include <hip/hip_runtime.h>

#define B_ 8
#define C_ 64
#define H_ 256
#define W_ 256
#define ST 32                 // output rows per wave/block strip
#define NCH 4                 // channels per thread
#define HW (H_ * W_)
#define WSTR (B_ * H_ * W_)   // weight tap stride in elements

// Rotating-partial-accumulator form: each arriving x row r contributes its 5
// horizontal taps to the 5 pending outputs h = r-2..r+2 (weight slice
// i = r-h+2). Live x state = current row (cur, 20) + one-step prefetch
// (pf, 20) + weights (25) + acc (20) ~= 95-110 VGPRs.
// R1 LESSON: __launch_bounds__(256,4) clamped the budget to 64 VGPRs ->
// ~40 regs spilled -> 840MB scratch writes, 7% VALUBusy, 4x regression.
// Plain __launch_bounds__(256) (v3-proven) restores the ~128 budget.
__global__ __launch_bounds__(256) void kpn5x5_v6(const float* __restrict__ x,
                                                 const float* __restrict__ wgt,
                                                 float* __restrict__ out) {
  const int tid  = threadIdx.x;
  const int lane = tid & 63;
  const int wv   = tid >> 6;               // 0..3
  const int w0   = blockIdx.x * 64;
  const int h0   = blockIdx.y * ST;
  const int bz   = blockIdx.z;             // = cgrp*8 + b (cgrp slowest ->
  const int b    = bz & 7;                 //   same-XCD weight sharing)
  const int c0   = (bz >> 3) * 16 + wv * NCH;

  // h-invariant per-thread column offsets (clamped) + 0/1 masks
  int   voff[5];
  float msk[5];
#pragma unroll
  for (int d = 0; d < 5; ++d) {
    const int col = w0 + lane - 2 + d;
    const bool ok = (col >= 0) && (col < W_);
    voff[d] = ok ? col : 0;
    msk[d]  = ok ? 1.0f : 0.0f;
  }

  // wave-uniform x/out bases -> force into SGPRs (saddr-form loads/stores)
  const float* xc;
  float* oc;
  {
    uint64_t px = (uint64_t)(x + (size_t)(b * C_ + c0) * HW);
    px = ((uint64_t)(uint32_t)__builtin_amdgcn_readfirstlane((int)(px >> 32)) << 32) |
         (uint64_t)(uint32_t)__builtin_amdgcn_readfirstlane((int)px);
    xc = (const float*)px;
    uint64_t po = (uint64_t)(out + (size_t)(b * C_ + c0) * HW);
    po = ((uint64_t)(uint32_t)__builtin_amdgcn_readfirstlane((int)(po >> 32)) << 32) |
         (uint64_t)(uint32_t)__builtin_amdgcn_readfirstlane((int)po);
    oc = (float*)po;
  }
  const float* wq = wgt + (size_t)b * HW + w0;   // block-uniform weight base

  float cur[NCH][5];   // taps of the arriving x row
  float pf[NCH][5];    // next x row (loaded one full step ahead)
  float wcs[5][5];     // per-pending-output weight slice (5 taps each)
  float acc[NCH][5];   // 5 rotating partial outputs per channel

#pragma unroll
  for (int ch = 0; ch < NCH; ++ch)
#pragma unroll
    for (int s = 0; s < 5; ++s) acc[ch][s] = 0.0f;

  // ---- prologue: pf <- x row h0-2 (consumed at step 0); wcs <- step-0 slices
  {
    const int r = h0 - 2;
    if (r >= 0) {
#pragma unroll
      for (int ch = 0; ch < NCH; ++ch) {
        const float* p = xc + ch * HW + r * W_;
#pragma unroll
        for (int d = 0; d < 5; ++d) pf[ch][d] = p[voff[d]];
      }
    } else {
#pragma unroll
      for (int ch = 0; ch < NCH; ++ch)
#pragma unroll
        for (int d = 0; d < 5; ++d) pf[ch][d] = 0.0f;
    }
    // step-0 segment j: tenant k=-j (phantom for j>0), slice i=j, slot (4-j)%5
#pragma unroll
    for (int j = 0; j < 5; ++j) {
      const int s = (4 - j) % 5;
      int hh = h0 - j;
      if (hh < 0) hh = 0;                       // clamp (phantom rows: garbage ok)
      const float* p = wq + (size_t)hh * W_;
#pragma unroll
      for (int d = 0; d < 5; ++d)
        wcs[s][d] = p[(size_t)(j * 5 + d) * WSTR + lane];
    }
  }

  // Step U (x row r = h0-2+U): mov pf->cur (masked), prefetch row r+1,
  // then 5 segments: segment j feeds tenant k=U-j (slot (S+4-j)%5, S=U%5)
  // and immediately reloads that slot's next-step weight slice in place.
  // Retiring segment (j==4) stores output h0+U-4 and resets its slot.
#define STEP(S, UO, DOST) do {                                               \
    const int u_ = ub + (UO);                                                \
    _Pragma("unroll")                                                        \
    for (int ch = 0; ch < NCH; ++ch)                                         \
      _Pragma("unroll")                                                      \
      for (int d = 0; d < 5; ++d) cur[ch][d] = pf[ch][d] * msk[d];           \
    {                                                                        \
      const int rb = h0 - 1 + u_;                                            \
      if ((unsigned)rb < (unsigned)H_) {                                     \
        _Pragma("unroll")                                                    \
        for (int ch = 0; ch < NCH; ++ch) {                                   \
          const float* p_ = xc + ch * HW + rb * W_;                          \
          _Pragma("unroll")                                                  \
          for (int d = 0; d < 5; ++d) pf[ch][d] = p_[voff[d]];               \
        }                                                                    \
      } else {                                                               \
        _Pragma("unroll")                                                    \
        for (int ch = 0; ch < NCH; ++ch)                                     \
          _Pragma("unroll")                                                  \
          for (int d = 0; d < 5; ++d) pf[ch][d] = 0.0f;                      \
      }                                                                      \
    }                                                                        \
    _Pragma("unroll")                                                        \
    for (int j = 0; j < 5; ++j) {                                            \
      const int s_ = ((S) + 4 - j) % 5;                                      \
      _Pragma("unroll")                                                      \
      for (int d = 0; d < 5; ++d) {                                          \
        const float wt_ = wcs[s_][d];                                        \
        _Pragma("unroll")                                                    \
        for (int ch = 0; ch < NCH; ++ch)                                     \
          acc[ch][s_] += cur[ch][d] * wt_;                                   \
      }                                                                      \
      if (j == 4) {                                                          \
        if (DOST) {                                                          \
          const size_t ob_ = (size_t)(h0 + u_ - 4) * W_ + w0 + lane;         \
          _Pragma("unroll")                                                  \
          for (int ch = 0; ch < NCH; ++ch)                                   \
            __builtin_nontemporal_store(acc[ch][(S)],                        \
                                        &oc[ob_ + (size_t)ch * HW]);         \
        }                                                                    \
        _Pragma("unroll")                                                    \
        for (int ch = 0; ch < NCH; ++ch) acc[ch][(S)] = 0.0f;                \
      }                                                                      \
      {                                                                      \
        int wr_ = (j == 4) ? (h0 + u_ + 1) : (h0 + u_ - j);                  \
        const int tb_ = (j == 4) ? 0 : (j + 1) * 5;                          \
        if (wr_ < 0) wr_ = 0;                                                \
        if (wr_ > H_ - 1) wr_ = H_ - 1;                                      \
        const float* pw_ = wq + (size_t)wr_ * W_;                            \
        _Pragma("unroll")                                                    \
        for (int d = 0; d < 5; ++d)                                          \
          wcs[s_][d] = pw_[(size_t)(tb_ + d) * WSTR + lane];                 \
      }                                                                      \
    }                                                                        \
  } while (0)

  int ub = 0;
  // 4 pipeline-fill steps (U=0..3): no stores, phantom slots get reset
  STEP(0, 0, false); STEP(1, 1, false); STEP(2, 2, false); STEP(3, 3, false);
  ub = 4;
#pragma unroll 1
  for (int g = 0; g < 6; ++g) {            // U = 4..33; keep body un-replicated
    STEP(4, 0, true); STEP(0, 1, true); STEP(1, 2, true);
    STEP(2, 3, true); STEP(3, 4, true);
    ub += 5;
  }
  STEP(4, 0, true); STEP(0, 1, true);      // U = 34, 35  (32 stores total)
#undef STEP
}

extern "C" void kernel_launch(void* const* d_in, const int* in_sizes, int n_in,
                              void* d_out, int out_size, void* d_ws, size_t ws_size,
                              hipStream_t stream) {
  const float* x   = (const float*)d_in[0];
  const float* wgt = (const float*)d_in[1];
  float* out = (float*)d_out;
  dim3 grid(W_ / 64, H_ / ST, (C_ / (NCH * 4)) * B_);  // 4 x 8 x 32 = 1024 blocks
  dim3 block(256);
  kpn5x5_v6<<<grid, block, 0, stream>>>(x, wgt, out);
}

// Round 5
// 337.849 us; speedup vs baseline: 2.5300x; 1.1173x over previous
//
#include <hip/hip_runtime.h>

#define B_ 8
#define C_ 64
#define H_ 256
#define W_ 256
#define ST 32                 // output rows per wave/block strip
#define NCH 4                 // channels per thread
#define HW (H_ * W_)
#define WSTR (B_ * H_ * W_)   // weight tap stride in elements

// Rotating-partial-accumulator form: each arriving x row r contributes its 5
// horizontal taps to the 5 pending outputs h = r-2..r+2 (weight slice
// i = r-h+2). Live x state = cur(20) + pf(20) + wcs(25) + acc(20) ~= 95-110.
// R1 LESSON: __launch_bounds__(256,4) => 64-VGPR budget => 40 spilled regs,
//            840MB scratch traffic, 4x regression.
// R2 LESSON: uncapped => 132 VGPR, 4 over the 128 granule => occupancy
//            halved (11.4%), 235us.
// R3/R4 LESSON: two container failures (one exotic-intrinsic kernel, one
//            near-identical to the verified R2 run) => infra flake, resubmit.
// => (256,2) pins the budget at exactly 128 (empirical mapping 256/k from R1).
__global__ __launch_bounds__(256, 2) void kpn5x5_v8(const float* __restrict__ x,
                                                    const float* __restrict__ wgt,
                                                    float* __restrict__ out) {
  const int tid  = threadIdx.x;
  const int lane = tid & 63;
  const int wv   = tid >> 6;               // 0..3
  const int w0   = blockIdx.x * 64;
  const int h0   = blockIdx.y * ST;
  const int bz   = blockIdx.z;             // = cgrp*8 + b (cgrp slowest ->
  const int b    = bz & 7;                 //   same-XCD weight sharing)
  const int c0   = (bz >> 3) * 16 + wv * NCH;

  // h-invariant per-thread column offsets (clamped) + 0/1 masks
  int   voff[5];
  float msk[5];
#pragma unroll
  for (int d = 0; d < 5; ++d) {
    const int col = w0 + lane - 2 + d;
    const bool ok = (col >= 0) && (col < W_);
    voff[d] = ok ? col : 0;
    msk[d]  = ok ? 1.0f : 0.0f;
  }

  // wave-uniform x/out bases -> force into SGPRs (saddr-form loads/stores)
  const float* xc;
  float* oc;
  {
    uint64_t px = (uint64_t)(x + (size_t)(b * C_ + c0) * HW);
    px = ((uint64_t)(uint32_t)__builtin_amdgcn_readfirstlane((int)(px >> 32)) << 32) |
         (uint64_t)(uint32_t)__builtin_amdgcn_readfirstlane((int)px);
    xc = (const float*)px;
    uint64_t po = (uint64_t)(out + (size_t)(b * C_ + c0) * HW);
    po = ((uint64_t)(uint32_t)__builtin_amdgcn_readfirstlane((int)(po >> 32)) << 32) |
         (uint64_t)(uint32_t)__builtin_amdgcn_readfirstlane((int)po);
    oc = (float*)po;
  }
  const float* wq = wgt + (size_t)b * HW + w0;   // block-uniform weight base

  float cur[NCH][5];   // taps of the arriving x row
  float pf[NCH][5];    // next x row (loaded one full step ahead)
  float wcs[5][5];     // per-pending-output weight slice (5 taps each)
  float acc[NCH][5];   // 5 rotating partial outputs per channel

#pragma unroll
  for (int ch = 0; ch < NCH; ++ch)
#pragma unroll
    for (int s = 0; s < 5; ++s) acc[ch][s] = 0.0f;

  // ---- prologue: pf <- x row h0-2 (consumed at step 0); wcs <- step-0 slices
  {
    const int r = h0 - 2;
    if (r >= 0) {
#pragma unroll
      for (int ch = 0; ch < NCH; ++ch) {
        const float* p = xc + ch * HW + r * W_;
#pragma unroll
        for (int d = 0; d < 5; ++d) pf[ch][d] = p[voff[d]];
      }
    } else {
#pragma unroll
      for (int ch = 0; ch < NCH; ++ch)
#pragma unroll
        for (int d = 0; d < 5; ++d) pf[ch][d] = 0.0f;
    }
    // step-0 segment j: tenant k=-j (phantom for j>0), slice i=j, slot (4-j)%5
#pragma unroll
    for (int j = 0; j < 5; ++j) {
      const int s = (4 - j) % 5;
      int hh = h0 - j;
      if (hh < 0) hh = 0;                       // clamp (phantom rows: garbage ok)
      const float* p = wq + (size_t)hh * W_;
#pragma unroll
      for (int d = 0; d < 5; ++d)
        wcs[s][d] = p[(size_t)(j * 5 + d) * WSTR + lane];
    }
  }

  // Step U (x row r = h0-2+U): mov pf->cur (masked), prefetch row r+1,
  // then 5 segments: segment j feeds tenant k=U-j (slot (S+4-j)%5, S=U%5)
  // and immediately reloads that slot's next-step weight slice in place.
  // Retiring segment (j==4) stores output h0+U-4 and resets its slot.
#define STEP(S, UO, DOST) do {                                               \
    const int u_ = ub + (UO);                                                \
    _Pragma("unroll")                                                        \
    for (int ch = 0; ch < NCH; ++ch)                                         \
      _Pragma("unroll")                                                      \
      for (int d = 0; d < 5; ++d) cur[ch][d] = pf[ch][d] * msk[d];           \
    {                                                                        \
      const int rb = h0 - 1 + u_;                                            \
      if ((unsigned)rb < (unsigned)H_) {   /* zero-pad semantics: required */\
        _Pragma("unroll")                                                    \
        for (int ch = 0; ch < NCH; ++ch) {                                   \
          const float* p_ = xc + ch * HW + rb * W_;                          \
          _Pragma("unroll")                                                  \
          for (int d = 0; d < 5; ++d) pf[ch][d] = p_[voff[d]];               \
        }                                                                    \
      } else {                                                               \
        _Pragma("unroll")                                                    \
        for (int ch = 0; ch < NCH; ++ch)                                     \
          _Pragma("unroll")                                                  \
          for (int d = 0; d < 5; ++d) pf[ch][d] = 0.0f;                      \
      }                                                                      \
    }                                                                        \
    _Pragma("unroll")                                                        \
    for (int j = 0; j < 5; ++j) {                                            \
      const int s_ = ((S) + 4 - j) % 5;                                      \
      _Pragma("unroll")                                                      \
      for (int d = 0; d < 5; ++d) {                                          \
        const float wt_ = wcs[s_][d];                                        \
        _Pragma("unroll")                                                    \
        for (int ch = 0; ch < NCH; ++ch)                                     \
          acc[ch][s_] += cur[ch][d] * wt_;                                   \
      }                                                                      \
      if (j == 4) {                                                          \
        if (DOST) {                                                          \
          const size_t ob_ = (size_t)(h0 + u_ - 4) * W_ + w0 + lane;         \
          _Pragma("unroll")                                                  \
          for (int ch = 0; ch < NCH; ++ch)                                   \
            __builtin_nontemporal_store(acc[ch][(S)],                        \
                                        &oc[ob_ + (size_t)ch * HW]);         \
        }                                                                    \
        _Pragma("unroll")                                                    \
        for (int ch = 0; ch < NCH; ++ch) acc[ch][(S)] = 0.0f;                \
      }                                                                      \
      {                                                                      \
        int wr_ = (j == 4) ? (h0 + u_ + 1) : (h0 + u_ - j);                  \
        const int tb_ = (j == 4) ? 0 : (j + 1) * 5;                          \
        if (wr_ < 0) wr_ = 0;                                                \
        if (wr_ > H_ - 1) wr_ = H_ - 1;                                      \
        const float* pw_ = wq + (size_t)wr_ * W_;                            \
        _Pragma("unroll")                                                    \
        for (int d = 0; d < 5; ++d)                                          \
          wcs[s_][d] = pw_[(size_t)(tb_ + d) * WSTR + lane];                 \
      }                                                                      \
    }                                                                        \
  } while (0)

  int ub = 0;
  // 4 pipeline-fill steps (U=0..3): no stores, phantom slots get reset
  STEP(0, 0, false); STEP(1, 1, false); STEP(2, 2, false); STEP(3, 3, false);
  ub = 4;
#pragma unroll 1
  for (int g = 0; g < 6; ++g) {            // U = 4..33; keep body un-replicated
    STEP(4, 0, true); STEP(0, 1, true); STEP(1, 2, true);
    STEP(2, 3, true); STEP(3, 4, true);
    ub += 5;
  }
  STEP(4, 0, true); STEP(0, 1, true);      // U = 34, 35  (32 stores total)
#undef STEP
}

extern "C" void kernel_launch(void* const* d_in, const int* in_sizes, int n_in,
                              void* d_out, int out_size, void* d_ws, size_t ws_size,
                              hipStream_t stream) {
  const float* x   = (const float*)d_in[0];
  const float* wgt = (const float*)d_in[1];
  float* out = (float*)d_out;
  dim3 grid(W_ / 64, H_ / ST, (C_ / (NCH * 4)) * B_);  // 4 x 8 x 32 = 1024 blocks
  dim3 block(256);
  kpn5x5_v8<<<grid, block, 0, stream>>>(x, wgt, out);
}